// Round 4
// baseline (13421.600 us; speedup 1.0000x reference)
//
#include <hip/hip_runtime.h>
#include <math.h>

#define HH   150        // hidden per direction
#define G4   600        // 4*H
#define DD   300        // embedding dim
#define CLS  7
#define SS   1024       // sentences
#define WW   128        // words per sentence
#define KCAT 450        // D + H
#define KPAD 456        // padded (456*4B % 16 == 0, 456/4 = 114 chunks)
#define K2PAD 152       // H padded to float4 multiple

__device__ __forceinline__ float sigf(float x) {
    return 1.0f / (1.0f + exp2f(-1.44269504088896341f * x));
}
__device__ __forceinline__ float tanh_f(float x) {
    return 2.0f / (1.0f + exp2f(-2.88539008177792681f * x)) - 1.0f;
}

// ---------------- weight packing ----------------
// Wcat: [2][600][KPAD] = [Wih row (300) | Whh row (150) | zeros(6)]
__global__ void pack1_kernel(const float* __restrict__ Wih_f, const float* __restrict__ Whh_f,
                             const float* __restrict__ Wih_b, const float* __restrict__ Whh_b,
                             float* __restrict__ Wcat) {
    int idx = blockIdx.x * 256 + threadIdx.x;
    const int total = 2 * G4 * KPAD;
    if (idx >= total) return;
    int k = idx % KPAD;
    int r = idx / KPAD;
    int o = r % G4;
    int dir = r / G4;
    const float* Wih = dir ? Wih_b : Wih_f;
    const float* Whh = dir ? Whh_b : Whh_f;
    float v = 0.0f;
    if (k < DD) v = Wih[o * DD + k];
    else if (k < KCAT) v = Whh[o * HH + (k - DD)];
    Wcat[idx] = v;
}

// W2cat: [2][600][K2PAD] = [Whh2 row (150) | zeros(2)]
__global__ void pack2_kernel(const float* __restrict__ Whh_f2, const float* __restrict__ Whh_b2,
                             float* __restrict__ W2cat) {
    int idx = blockIdx.x * 256 + threadIdx.x;
    const int total = 2 * G4 * K2PAD;
    if (idx >= total) return;
    int k = idx % K2PAD;
    int r = idx / K2PAD;
    int o = r % G4;
    int dir = r / G4;
    const float* Whh = dir ? Whh_b2 : Whh_f2;
    float v = (k < HH) ? Whh[o * HH + k] : 0.0f;
    W2cat[idx] = v;
}

// ---------------- word-level BiLSTM (stage 1) ----------------
// grid 256 = 128 sentence-blocks x 2 dirs; block 320 (5 waves).
// R=2 rows/thread: threads 0..299 each own output rows 2t, 2t+1.
// Each LDS broadcast read of xh (ds_read_b128) now feeds 2 rows' FMAs in
// registers -> LDS instr/step halves vs the R=1 version (the measured
// bottleneck: 110k cyc/step, 94% explained by 8.5k broadcast b128 @ ~12cyc).
__global__ __launch_bounds__(320, 1) void word_lstm_kernel(
    const float* __restrict__ x,        // [S][W][D]
    const float* __restrict__ Wcat,     // [2][600][KPAD]
    const float* __restrict__ bih_f, const float* __restrict__ bhh_f,
    const float* __restrict__ bih_b, const float* __restrict__ bhh_b,
    float* __restrict__ sent_emb)       // [S][300]
{
    __shared__ __align__(16) float xh[8][KPAD];   // [x(300) | h(150) | pad0(6)]
    __shared__ __align__(16) float g[8][G4];
    __shared__ __align__(16) float cst[8][HH];
    __shared__ __align__(16) float hmax[8][HH];

    const int tid = threadIdx.x;
    const int dir = blockIdx.x & 1;
    const int sb  = blockIdx.x >> 1;
    const int s0  = sb * 8;

    for (int i = tid; i < 8 * KPAD; i += 320) ((float*)xh)[i] = 0.0f;  // h0=0, pads=0
    for (int i = tid; i < 8 * HH; i += 320) {
        ((float*)cst)[i] = 0.0f;
        ((float*)hmax)[i] = -INFINITY;
    }

    const float4* wr0 = nullptr;
    const float4* wr1 = nullptr;
    float bias0 = 0.0f, bias1 = 0.0f;
    if (tid < 300) {
        const int r0 = 2 * tid, r1 = 2 * tid + 1;
        wr0 = (const float4*)(Wcat + ((size_t)dir * G4 + r0) * KPAD);
        wr1 = (const float4*)(Wcat + ((size_t)dir * G4 + r1) * KPAD);
        if (dir) { bias0 = bih_b[r0] + bhh_b[r0]; bias1 = bih_b[r1] + bhh_b[r1]; }
        else     { bias0 = bih_f[r0] + bhh_f[r0]; bias1 = bih_f[r1] + bhh_f[r1]; }
    }

    // prologue: stage x for first time index
    {
        int t0 = (dir == 0) ? 0 : (WW - 1);
        __syncthreads();
        for (int i = tid; i < 8 * DD; i += 320) {
            int s = i / DD, d = i - s * DD;
            xh[s][d] = x[((size_t)(s0 + s) * WW + t0) * DD + d];
        }
    }
    __syncthreads();

    for (int st = 0; st < WW; ++st) {
        const int tt = (dir == 0) ? st : (WW - 1 - st);
        const int tn = (dir == 0) ? (tt + 1) : (tt - 1);
        const bool has_next = (st + 1 < WW);

        // prefetch next x into registers (2400 vals over 320 threads = 8 slots)
        float pf[8];
        if (has_next) {
            #pragma unroll
            for (int k = 0; k < 8; ++k) {
                int i = tid + k * 320;
                if (k < 7 || i < 8 * DD) {
                    int s = i / DD, d = i - s * DD;
                    pf[k] = x[((size_t)(s0 + s) * WW + tn) * DD + d];
                }
            }
        }

        // dot phase: g[s][r] = bias_r + [x|h] . Wcat[r], 2 rows per thread
        if (tid < 300) {
            float acc0[8], acc1[8];
            #pragma unroll
            for (int s = 0; s < 8; ++s) { acc0[s] = bias0; acc1[s] = bias1; }
            #pragma unroll 2
            for (int kc = 0; kc < KPAD / 4; ++kc) {
                float4 w0 = wr0[kc];
                float4 w1 = wr1[kc];
                #pragma unroll
                for (int s = 0; s < 8; ++s) {
                    float4 xv = *((const float4*)&xh[s][kc * 4]);
                    acc0[s] = fmaf(w0.x, xv.x, acc0[s]);
                    acc0[s] = fmaf(w0.y, xv.y, acc0[s]);
                    acc0[s] = fmaf(w0.z, xv.z, acc0[s]);
                    acc0[s] = fmaf(w0.w, xv.w, acc0[s]);
                    acc1[s] = fmaf(w1.x, xv.x, acc1[s]);
                    acc1[s] = fmaf(w1.y, xv.y, acc1[s]);
                    acc1[s] = fmaf(w1.z, xv.z, acc1[s]);
                    acc1[s] = fmaf(w1.w, xv.w, acc1[s]);
                }
            }
            #pragma unroll
            for (int s = 0; s < 8; ++s) {
                *((float2*)&g[s][2 * tid]) = make_float2(acc0[s], acc1[s]);
            }
        }
        __syncthreads();

        // gate phase: 1200 units over 320 threads
        for (int u = tid; u < 8 * HH; u += 320) {
            int s = u / HH, uu = u - s * HH;
            float gi = g[s][uu], gf = g[s][HH + uu], gg = g[s][2 * HH + uu], go = g[s][3 * HH + uu];
            float c = cst[s][uu];
            c = sigf(gf) * c + sigf(gi) * tanh_f(gg);
            float h = sigf(go) * tanh_f(c);
            cst[s][uu] = c;
            xh[s][DD + uu] = h;
            hmax[s][uu] = fmaxf(hmax[s][uu], h);
        }

        // write prefetched x for next step
        if (has_next) {
            #pragma unroll
            for (int k = 0; k < 8; ++k) {
                int i = tid + k * 320;
                if (k < 7 || i < 8 * DD) {
                    int s = i / DD, d = i - s * DD;
                    xh[s][d] = pf[k];
                }
            }
        }
        __syncthreads();
    }

    for (int u = tid; u < 8 * HH; u += 320) {
        int s = u / HH, uu = u - s * HH;
        sent_emb[(size_t)(s0 + s) * DD + dir * HH + uu] = hmax[s][uu];
    }
}

// ---------------- stage-2 input projection ----------------
// grid 2048 = 1024 t x 2 dirs, block 256. xw2[dir][t][600]
__global__ void xw2_kernel(const float* __restrict__ sent_emb,
                           const float* __restrict__ Wih_f2, const float* __restrict__ bih_f2,
                           const float* __restrict__ bhh_f2,
                           const float* __restrict__ Wih_b2, const float* __restrict__ bih_b2,
                           const float* __restrict__ bhh_b2,
                           float* __restrict__ xw2) {
    __shared__ __align__(16) float xr[DD];
    const int t = blockIdx.x >> 1;
    const int dir = blockIdx.x & 1;
    const float* Wih2 = dir ? Wih_b2 : Wih_f2;
    const float* ba = dir ? bih_b2 : bih_f2;
    const float* bb = dir ? bhh_b2 : bhh_f2;
    for (int i = threadIdx.x; i < DD; i += 256) xr[i] = sent_emb[(size_t)t * DD + i];
    __syncthreads();
    for (int o = threadIdx.x; o < G4; o += 256) {
        float acc = ba[o] + bb[o];
        const float4* wr = (const float4*)(Wih2 + (size_t)o * DD);
        #pragma unroll 4
        for (int kc = 0; kc < DD / 4; ++kc) {
            float4 w4 = wr[kc];
            float4 xv = *((const float4*)&xr[kc * 4]);
            acc = fmaf(w4.x, xv.x, acc);
            acc = fmaf(w4.y, xv.y, acc);
            acc = fmaf(w4.z, xv.z, acc);
            acc = fmaf(w4.w, xv.w, acc);
        }
        xw2[((size_t)dir * SS + t) * G4 + o] = acc;
    }
}

// ---------------- sentence-level BiLSTM (stage 2) ----------------
// grid 2 (dir), block 320 (5 waves). R=2 rows/thread: Whh2 resident in
// registers (2x38 float4 = 304 VGPR), halving waves -> halves the per-step
// broadcast ds_read_b128 count. Next step's xw2 row prefetched into
// registers so the global-load latency hides under the previous gate phase.
__global__ __launch_bounds__(320, 1) void sent_lstm_kernel(
    const float* __restrict__ W2cat,    // [2][600][K2PAD]
    const float* __restrict__ xw2,      // [2][S][600]
    float* __restrict__ sent_out)       // [S][300]
{
    __shared__ __align__(16) float hl[K2PAD];
    __shared__ __align__(16) float g[G4];
    const int dir = blockIdx.x;
    const int tid = threadIdx.x;

    float4 wv0[K2PAD / 4], wv1[K2PAD / 4];
    if (tid < 300) {
        const float4* wr0 = (const float4*)(W2cat + ((size_t)dir * G4 + 2 * tid) * K2PAD);
        const float4* wr1 = (const float4*)(W2cat + ((size_t)dir * G4 + 2 * tid + 1) * K2PAD);
        #pragma unroll
        for (int j = 0; j < K2PAD / 4; ++j) { wv0[j] = wr0[j]; wv1[j] = wr1[j]; }
    }
    for (int i = tid; i < K2PAD; i += 320) hl[i] = 0.0f;
    float c = 0.0f;  // owned by tid < 150

    // prefetch first step's xw2 row pair
    float2 xwc = make_float2(0.0f, 0.0f);
    if (tid < 300) {
        const int t0 = dir ? (SS - 1) : 0;
        xwc = *((const float2*)&xw2[((size_t)dir * SS + t0) * G4 + 2 * tid]);
    }
    __syncthreads();

    for (int st = 0; st < SS; ++st) {
        const int tt = dir ? (SS - 1 - st) : st;

        // prefetch next step's xw2 (off critical path)
        float2 xwn = xwc;
        if (st + 1 < SS && tid < 300) {
            const int tn = dir ? (SS - 2 - st) : (st + 1);
            xwn = *((const float2*)&xw2[((size_t)dir * SS + tn) * G4 + 2 * tid]);
        }

        if (tid < 300) {
            float a0 = 0.f, a1 = 0.f, a2 = 0.f, a3 = 0.f;
            float b0 = 0.f, b1 = 0.f, b2 = 0.f, b3 = 0.f;
            #pragma unroll
            for (int j = 0; j < K2PAD / 4; ++j) {
                float4 h4 = *((const float4*)&hl[j * 4]);
                a0 = fmaf(wv0[j].x, h4.x, a0);
                a1 = fmaf(wv0[j].y, h4.y, a1);
                a2 = fmaf(wv0[j].z, h4.z, a2);
                a3 = fmaf(wv0[j].w, h4.w, a3);
                b0 = fmaf(wv1[j].x, h4.x, b0);
                b1 = fmaf(wv1[j].y, h4.y, b1);
                b2 = fmaf(wv1[j].z, h4.z, b2);
                b3 = fmaf(wv1[j].w, h4.w, b3);
            }
            *((float2*)&g[2 * tid]) = make_float2(
                xwc.x + ((a0 + a1) + (a2 + a3)),
                xwc.y + ((b0 + b1) + (b2 + b3)));
        }
        __syncthreads();
        if (tid < HH) {
            float gi = g[tid], gf = g[HH + tid], gg = g[2 * HH + tid], go = g[3 * HH + tid];
            c = sigf(gf) * c + sigf(gi) * tanh_f(gg);
            float h = sigf(go) * tanh_f(c);
            hl[tid] = h;
            sent_out[(size_t)tt * DD + dir * HH + tid] = h;
        }
        xwc = xwn;
        __syncthreads();
    }
}

// ---------------- classification + loss ----------------
// grid 1024 (one wave per sentence)
__global__ void loss_kernel(const float* __restrict__ sent_out,
                            const int* __restrict__ gold,
                            const float* __restrict__ W_out, const float* __restrict__ b_out,
                            const float* __restrict__ last_rep,
                            float* __restrict__ d_out, float* __restrict__ loss_arr) {
    const int t = blockIdx.x;
    const int lane = threadIdx.x;
    const float* a = sent_out + (size_t)t * DD;

    float pl[CLS];
    #pragma unroll
    for (int j = 0; j < CLS; ++j) pl[j] = 0.0f;
    float na2 = 0.0f;
    for (int k = lane; k < DD; k += 64) {
        float av = a[k];
        na2 = fmaf(av, av, na2);
        #pragma unroll
        for (int j = 0; j < CLS; ++j) pl[j] = fmaf(av, W_out[j * DD + k], pl[j]);
    }
    #pragma unroll
    for (int off = 32; off > 0; off >>= 1) {
        na2 += __shfl_down(na2, off);
        #pragma unroll
        for (int j = 0; j < CLS; ++j) pl[j] += __shfl_down(pl[j], off);
    }

    int pre = 0;
    float nll = 0.0f, nrm_a = 1.0f;
    if (lane == 0) {
        float lg[CLS];
        float mx = -INFINITY;
        #pragma unroll
        for (int j = 0; j < CLS; ++j) {
            lg[j] = pl[j] + b_out[j];
            if (lg[j] > mx) mx = lg[j];
        }
        pre = 0;
        float bst = lg[0];
        #pragma unroll
        for (int j = 1; j < CLS; ++j) {       // first-max semantics (strict >)
            if (lg[j] > bst) { bst = lg[j]; pre = j; }
        }
        float se = 0.0f;
        #pragma unroll
        for (int j = 0; j < CLS; ++j) se += expf(lg[j] - mx);
        float lse = logf(se);
        nll = -(lg[gold[t]] - mx - lse);
        nrm_a = fmaxf(sqrtf(na2), 1e-8f);
    }
    pre = __shfl(pre, 0);

    const float* lr = last_rep + (size_t)pre * DD;
    float dp = 0.0f, nb2 = 0.0f;
    for (int k = lane; k < DD; k += 64) {
        float bv = lr[k];
        dp = fmaf(a[k], bv, dp);
        nb2 = fmaf(bv, bv, nb2);
    }
    #pragma unroll
    for (int off = 32; off > 0; off >>= 1) {
        dp += __shfl_down(dp, off);
        nb2 += __shfl_down(nb2, off);
    }
    if (lane == 0) {
        float nb = fmaxf(sqrtf(nb2), 1e-8f);
        float sim = dp / (nrm_a * nb);
        float lt = nll + ((pre != gold[t]) ? sim : 0.0f);
        loss_arr[t] = lt;
        d_out[t] = (float)pre;
    }
}

__global__ void reduce_loss_kernel(const float* __restrict__ loss_arr, float* __restrict__ out_loss) {
    __shared__ float sm[256];
    float s = 0.0f;
    for (int i = threadIdx.x; i < SS; i += 256) s += loss_arr[i];
    sm[threadIdx.x] = s;
    __syncthreads();
    for (int stp = 128; stp > 0; stp >>= 1) {
        if (threadIdx.x < stp) sm[threadIdx.x] += sm[threadIdx.x + stp];
        __syncthreads();
    }
    if (threadIdx.x == 0) out_loss[0] = sm[0];
}

extern "C" void kernel_launch(void* const* d_in, const int* in_sizes, int n_in,
                              void* d_out, int out_size, void* d_ws, size_t ws_size,
                              hipStream_t stream) {
    const float* x       = (const float*)d_in[0];
    const int*   gold    = (const int*)d_in[1];
    const float* Wih_f1  = (const float*)d_in[2];
    const float* Whh_f1  = (const float*)d_in[3];
    const float* bih_f1  = (const float*)d_in[4];
    const float* bhh_f1  = (const float*)d_in[5];
    const float* Wih_b1  = (const float*)d_in[6];
    const float* Whh_b1  = (const float*)d_in[7];
    const float* bih_b1  = (const float*)d_in[8];
    const float* bhh_b1  = (const float*)d_in[9];
    const float* Wih_f2  = (const float*)d_in[10];
    const float* Whh_f2  = (const float*)d_in[11];
    const float* bih_f2  = (const float*)d_in[12];
    const float* bhh_f2  = (const float*)d_in[13];
    const float* Wih_b2  = (const float*)d_in[14];
    const float* Whh_b2  = (const float*)d_in[15];
    const float* bih_b2  = (const float*)d_in[16];
    const float* bhh_b2  = (const float*)d_in[17];
    const float* W_out   = (const float*)d_in[18];
    const float* b_out   = (const float*)d_in[19];
    const float* last_rep= (const float*)d_in[20];

    float* ws = (float*)d_ws;
    float* Wcat     = ws;                         // 2*600*456   = 547200
    float* W2cat    = Wcat + 2 * G4 * KPAD;       // 2*600*152   = 182400
    float* sent_emb = W2cat + 2 * G4 * K2PAD;     // 1024*300    = 307200
    float* xw2      = sent_emb + SS * DD;         // 2*1024*600  = 1228800
    float* sent_out = xw2 + 2 * SS * G4;          // 1024*300    = 307200
    float* loss_arr = sent_out + SS * DD;         // 1024
    // total ~10.3 MB of workspace

    pack1_kernel<<<(2 * G4 * KPAD + 255) / 256, 256, 0, stream>>>(Wih_f1, Whh_f1, Wih_b1, Whh_b1, Wcat);
    pack2_kernel<<<(2 * G4 * K2PAD + 255) / 256, 256, 0, stream>>>(Whh_f2, Whh_b2, W2cat);
    word_lstm_kernel<<<256, 320, 0, stream>>>(x, Wcat, bih_f1, bhh_f1, bih_b1, bhh_b1, sent_emb);
    xw2_kernel<<<2048, 256, 0, stream>>>(sent_emb, Wih_f2, bih_f2, bhh_f2, Wih_b2, bih_b2, bhh_b2, xw2);
    sent_lstm_kernel<<<2, 320, 0, stream>>>(W2cat, xw2, sent_out);
    loss_kernel<<<1024, 64, 0, stream>>>(sent_out, gold, W_out, b_out, last_rep, (float*)d_out, loss_arr);
    reduce_loss_kernel<<<1, 256, 0, stream>>>(loss_arr, (float*)d_out + SS);
}

// Round 8
// 10446.260 us; speedup vs baseline: 1.2848x; 1.2848x over previous
//
#include <hip/hip_runtime.h>
#include <math.h>

#define HH   150        // hidden per direction
#define G4   600        // 4*H
#define DD   300        // embedding dim
#define CLS  7
#define SS   1024       // sentences
#define WW   128        // words per sentence
#define KCAT 450        // D + H
#define KPAD 456        // padded k for stage-1 (114 float4 chunks)
#define NKC  114        // KPAD/4
#define K2PAD 152       // H padded to float4 multiple (38 chunks)

__device__ __forceinline__ float sigf(float x) {
    return 1.0f / (1.0f + exp2f(-1.44269504088896341f * x));
}
__device__ __forceinline__ float tanh_f(float x) {
    return 2.0f / (1.0f + exp2f(-2.88539008177792681f * x)) - 1.0f;
}

// ---------------- weight packing ----------------
// Wkm: k-major [2][NKC][600] float4: Wkm[dir][kc][r] = W[r][4kc..4kc+3]
// -> lanes (consecutive rows) load at 16/32B stride = coalesced streaming.
__global__ void pack1_kernel(const float* __restrict__ Wih_f, const float* __restrict__ Whh_f,
                             const float* __restrict__ Wih_b, const float* __restrict__ Whh_b,
                             float* __restrict__ Wkm) {
    int idx = blockIdx.x * 256 + threadIdx.x;   // one float4 per (dir,kc,r)
    const int total = 2 * NKC * G4;
    if (idx >= total) return;
    int r   = idx % G4;
    int kc  = (idx / G4) % NKC;
    int dir = idx / (G4 * NKC);
    const float* Wih = dir ? Wih_b : Wih_f;
    const float* Whh = dir ? Whh_b : Whh_f;
    float v[4];
    #pragma unroll
    for (int e = 0; e < 4; ++e) {
        int k = 4 * kc + e;
        float t = 0.0f;
        if (k < DD) t = Wih[r * DD + k];
        else if (k < KCAT) t = Whh[r * HH + (k - DD)];
        v[e] = t;
    }
    ((float4*)Wkm)[idx] = make_float4(v[0], v[1], v[2], v[3]);
}

// W2cat: [2][600][K2PAD] = [Whh2 row (150) | zeros(2)]
__global__ void pack2_kernel(const float* __restrict__ Whh_f2, const float* __restrict__ Whh_b2,
                             float* __restrict__ W2cat) {
    int idx = blockIdx.x * 256 + threadIdx.x;
    const int total = 2 * G4 * K2PAD;
    if (idx >= total) return;
    int k = idx % K2PAD;
    int r = idx / K2PAD;
    int o = r % G4;
    int dir = r / G4;
    const float* Whh = dir ? Whh_b2 : Whh_f2;
    float v = (k < HH) ? Whh[o * HH + k] : 0.0f;
    W2cat[idx] = v;
}

// ---------------- word-level BiLSTM (stage 1) ----------------
// grid 256 = 128 sentence-blocks x 2 dirs; block 640 (10 waves).
// R=2 rows/thread WITH sentence-split to keep 10 waves (round-4 lesson:
// 5 waves is latency-bound): threads 0-299 own rows (2u,2u+1) x sentences
// 0-3; threads 320-619 same rows x sentences 4-7. LDS broadcast b128 count
// per step is halved vs R=1 (4275 vs 8550) at unchanged occupancy.
// Duplicate weight loads (u and u+320, same addr, ~same time) hit L1.
__global__ __launch_bounds__(640, 1) void word_lstm_kernel(
    const float* __restrict__ x,        // [S][W][D]
    const float* __restrict__ Wkm,      // [2][NKC][600] float4 k-major
    const float* __restrict__ bih_f, const float* __restrict__ bhh_f,
    const float* __restrict__ bih_b, const float* __restrict__ bhh_b,
    float* __restrict__ sent_emb)       // [S][300]
{
    __shared__ __align__(16) float xh[8][KPAD];   // [x(300) | h(150) | pad0(6)]
    __shared__ __align__(16) float g[8][G4];
    __shared__ __align__(16) float cst[8][HH];
    __shared__ __align__(16) float hmax[8][HH];

    const int tid = threadIdx.x;
    const int dir = blockIdx.x & 1;
    const int sb  = blockIdx.x >> 1;
    const int s0  = sb * 8;

    const int grp   = (tid >= 320) ? 1 : 0;
    const int u     = tid - 320 * grp;       // 0..319
    const bool owner = (u < 300);
    const int sbase = 4 * grp;               // this thread's sentences [sbase, sbase+4)

    for (int i = tid; i < 8 * KPAD; i += 640) ((float*)xh)[i] = 0.0f;  // h0=0, pads=0
    for (int i = tid; i < 8 * HH; i += 640) {
        ((float*)cst)[i] = 0.0f;
        ((float*)hmax)[i] = -INFINITY;
    }

    const float4* wbase = ((const float4*)Wkm) + (size_t)dir * NKC * G4;
    float bias0 = 0.0f, bias1 = 0.0f;
    if (owner) {
        const int r0 = 2 * u, r1 = 2 * u + 1;
        if (dir) { bias0 = bih_b[r0] + bhh_b[r0]; bias1 = bih_b[r1] + bhh_b[r1]; }
        else     { bias0 = bih_f[r0] + bhh_f[r0]; bias1 = bih_f[r1] + bhh_f[r1]; }
    }

    // prologue: stage x for first time index
    {
        int t0 = (dir == 0) ? 0 : (WW - 1);
        __syncthreads();
        for (int i = tid; i < 8 * DD; i += 640) {
            int s = i / DD, d = i - s * DD;
            xh[s][d] = x[((size_t)(s0 + s) * WW + t0) * DD + d];
        }
    }
    __syncthreads();

    for (int st = 0; st < WW; ++st) {
        const int tt = (dir == 0) ? st : (WW - 1 - st);
        const int tn = (dir == 0) ? (tt + 1) : (tt - 1);
        const bool has_next = (st + 1 < WW);

        // prefetch next x into registers (2400 vals over 640 threads = 4 slots)
        float pf[4];
        if (has_next) {
            #pragma unroll
            for (int k = 0; k < 4; ++k) {
                int i = tid + k * 640;
                if (k < 3 || i < 8 * DD) {
                    int s = i / DD, d = i - s * DD;
                    pf[k] = x[((size_t)(s0 + s) * WW + tn) * DD + d];
                }
            }
        }

        // dot phase: g[s][r] = bias_r + [x|h] . W[r], 2 rows x 4 sentences
        if (owner) {
            float acc0[4], acc1[4];
            #pragma unroll
            for (int q = 0; q < 4; ++q) { acc0[q] = bias0; acc1[q] = bias1; }
            #pragma unroll 2
            for (int kc = 0; kc < NKC; ++kc) {
                float4 w0 = wbase[kc * G4 + 2 * u];
                float4 w1 = wbase[kc * G4 + 2 * u + 1];
                #pragma unroll
                for (int q = 0; q < 4; ++q) {
                    float4 xv = *((const float4*)&xh[sbase + q][kc * 4]);
                    acc0[q] = fmaf(w0.x, xv.x, acc0[q]);
                    acc0[q] = fmaf(w0.y, xv.y, acc0[q]);
                    acc0[q] = fmaf(w0.z, xv.z, acc0[q]);
                    acc0[q] = fmaf(w0.w, xv.w, acc0[q]);
                    acc1[q] = fmaf(w1.x, xv.x, acc1[q]);
                    acc1[q] = fmaf(w1.y, xv.y, acc1[q]);
                    acc1[q] = fmaf(w1.z, xv.z, acc1[q]);
                    acc1[q] = fmaf(w1.w, xv.w, acc1[q]);
                }
            }
            #pragma unroll
            for (int q = 0; q < 4; ++q) {
                *((float2*)&g[sbase + q][2 * u]) = make_float2(acc0[q], acc1[q]);
            }
        }
        __syncthreads();

        // gate phase: 1200 units over 640 threads
        for (int v = tid; v < 8 * HH; v += 640) {
            int s = v / HH, uu = v - s * HH;
            float gi = g[s][uu], gf = g[s][HH + uu], gg = g[s][2 * HH + uu], go = g[s][3 * HH + uu];
            float c = cst[s][uu];
            c = sigf(gf) * c + sigf(gi) * tanh_f(gg);
            float h = sigf(go) * tanh_f(c);
            cst[s][uu] = c;
            xh[s][DD + uu] = h;
            hmax[s][uu] = fmaxf(hmax[s][uu], h);
        }

        // write prefetched x for next step (disjoint from h region)
        if (has_next) {
            #pragma unroll
            for (int k = 0; k < 4; ++k) {
                int i = tid + k * 640;
                if (k < 3 || i < 8 * DD) {
                    int s = i / DD, d = i - s * DD;
                    xh[s][d] = pf[k];
                }
            }
        }
        __syncthreads();
    }

    for (int v = tid; v < 8 * HH; v += 640) {
        int s = v / HH, uu = v - s * HH;
        sent_emb[(size_t)(s0 + s) * DD + dir * HH + uu] = hmax[s][uu];
    }
}

// ---------------- stage-2 input projection ----------------
// grid 2048 = 1024 t x 2 dirs, block 256. xw2[dir][t][600]
__global__ void xw2_kernel(const float* __restrict__ sent_emb,
                           const float* __restrict__ Wih_f2, const float* __restrict__ bih_f2,
                           const float* __restrict__ bhh_f2,
                           const float* __restrict__ Wih_b2, const float* __restrict__ bih_b2,
                           const float* __restrict__ bhh_b2,
                           float* __restrict__ xw2) {
    __shared__ __align__(16) float xr[DD];
    const int t = blockIdx.x >> 1;
    const int dir = blockIdx.x & 1;
    const float* Wih2 = dir ? Wih_b2 : Wih_f2;
    const float* ba = dir ? bih_b2 : bih_f2;
    const float* bb = dir ? bhh_b2 : bhh_f2;
    for (int i = threadIdx.x; i < DD; i += 256) xr[i] = sent_emb[(size_t)t * DD + i];
    __syncthreads();
    for (int o = threadIdx.x; o < G4; o += 256) {
        float acc = ba[o] + bb[o];
        const float4* wr = (const float4*)(Wih2 + (size_t)o * DD);
        #pragma unroll 4
        for (int kc = 0; kc < DD / 4; ++kc) {
            float4 w4 = wr[kc];
            float4 xv = *((const float4*)&xr[kc * 4]);
            acc = fmaf(w4.x, xv.x, acc);
            acc = fmaf(w4.y, xv.y, acc);
            acc = fmaf(w4.z, xv.z, acc);
            acc = fmaf(w4.w, xv.w, acc);
        }
        xw2[((size_t)dir * SS + t) * G4 + o] = acc;
    }
}

// ---------------- sentence-level BiLSTM (stage 2) ----------------
// grid 2 (dir), block 640 (10 waves). R=1 (152 weight VGPRs -> no spill at
// 10-wave cap; round-4's R=2 at 304 VGPRs spilled). Wave-local gates:
// wave w owns units 16w..16w+15; lane = (gate, uu); the 4 gate values of a
// unit meet via 3 __shfl_down (no g[] LDS round-trip). h double-buffered
// in LDS -> ONE barrier per step instead of two.
__global__ __launch_bounds__(640, 1) void sent_lstm_kernel(
    const float* __restrict__ W2cat,    // [2][600][K2PAD]
    const float* __restrict__ xw2,      // [2][S][600]
    float* __restrict__ sent_out)       // [S][300]
{
    __shared__ __align__(16) float hl[2][K2PAD];
    const int dir  = blockIdx.x;
    const int tid  = threadIdx.x;
    const int w    = tid >> 6;
    const int lane = tid & 63;
    const int gate = lane >> 4;          // 0:i 1:f 2:g 3:o
    const int uu   = lane & 15;
    const int unit = 16 * w + uu;
    const bool active = (unit < HH);
    const int row  = gate * HH + unit;   // row in [0,600)

    float4 wv[K2PAD / 4];
    if (active) {
        const float4* wr = (const float4*)(W2cat + ((size_t)dir * G4 + row) * K2PAD);
        #pragma unroll
        for (int j = 0; j < K2PAD / 4; ++j) wv[j] = wr[j];
    }
    for (int i = tid; i < 2 * K2PAD; i += 640) ((float*)hl)[i] = 0.0f;
    float c = 0.0f;                      // owned by gate==0 lanes

    // prefetch first step's xw2 value
    float xwc = 0.0f;
    if (active) {
        const int t0 = dir ? (SS - 1) : 0;
        xwc = xw2[((size_t)dir * SS + t0) * G4 + row];
    }
    __syncthreads();

    int cur = 0;
    for (int st = 0; st < SS; ++st) {
        const int tt = dir ? (SS - 1 - st) : st;

        // prefetch next step's xw2 (off critical path)
        float xwn = 0.0f;
        if (st + 1 < SS && active) {
            const int tn = dir ? (SS - 2 - st) : (st + 1);
            xwn = xw2[((size_t)dir * SS + tn) * G4 + row];
        }

        float gv = 0.0f;
        if (active) {
            float a0 = 0.f, a1 = 0.f, a2 = 0.f, a3 = 0.f;
            #pragma unroll
            for (int j = 0; j < K2PAD / 4; ++j) {
                float4 h4 = *((const float4*)&hl[cur][4 * j]);
                a0 = fmaf(wv[j].x, h4.x, a0);
                a1 = fmaf(wv[j].y, h4.y, a1);
                a2 = fmaf(wv[j].z, h4.z, a2);
                a3 = fmaf(wv[j].w, h4.w, a3);
            }
            gv = xwc + ((a0 + a1) + (a2 + a3));
        }
        // bring f,g,o gate values to the i-gate lane of each unit
        float gf = __shfl_down(gv, 16);
        float gg = __shfl_down(gv, 32);
        float go = __shfl_down(gv, 48);
        if (gate == 0 && active) {
            c = sigf(gf) * c + sigf(gv) * tanh_f(gg);
            float h = sigf(go) * tanh_f(c);
            hl[cur ^ 1][unit] = h;
            sent_out[(size_t)tt * DD + dir * HH + unit] = h;
        }
        __syncthreads();   // all dots done reading hl[cur]; hl[cur^1] complete
        cur ^= 1;
        xwc = xwn;
    }
}

// ---------------- classification + loss ----------------
// grid 1024 (one wave per sentence)
__global__ void loss_kernel(const float* __restrict__ sent_out,
                            const int* __restrict__ gold,
                            const float* __restrict__ W_out, const float* __restrict__ b_out,
                            const float* __restrict__ last_rep,
                            float* __restrict__ d_out, float* __restrict__ loss_arr) {
    const int t = blockIdx.x;
    const int lane = threadIdx.x;
    const float* a = sent_out + (size_t)t * DD;

    float pl[CLS];
    #pragma unroll
    for (int j = 0; j < CLS; ++j) pl[j] = 0.0f;
    float na2 = 0.0f;
    for (int k = lane; k < DD; k += 64) {
        float av = a[k];
        na2 = fmaf(av, av, na2);
        #pragma unroll
        for (int j = 0; j < CLS; ++j) pl[j] = fmaf(av, W_out[j * DD + k], pl[j]);
    }
    #pragma unroll
    for (int off = 32; off > 0; off >>= 1) {
        na2 += __shfl_down(na2, off);
        #pragma unroll
        for (int j = 0; j < CLS; ++j) pl[j] += __shfl_down(pl[j], off);
    }

    int pre = 0;
    float nll = 0.0f, nrm_a = 1.0f;
    if (lane == 0) {
        float lg[CLS];
        float mx = -INFINITY;
        #pragma unroll
        for (int j = 0; j < CLS; ++j) {
            lg[j] = pl[j] + b_out[j];
            if (lg[j] > mx) mx = lg[j];
        }
        pre = 0;
        float bst = lg[0];
        #pragma unroll
        for (int j = 1; j < CLS; ++j) {       // first-max semantics (strict >)
            if (lg[j] > bst) { bst = lg[j]; pre = j; }
        }
        float se = 0.0f;
        #pragma unroll
        for (int j = 0; j < CLS; ++j) se += expf(lg[j] - mx);
        float lse = logf(se);
        nll = -(lg[gold[t]] - mx - lse);
        nrm_a = fmaxf(sqrtf(na2), 1e-8f);
    }
    pre = __shfl(pre, 0);

    const float* lr = last_rep + (size_t)pre * DD;
    float dp = 0.0f, nb2 = 0.0f;
    for (int k = lane; k < DD; k += 64) {
        float bv = lr[k];
        dp = fmaf(a[k], bv, dp);
        nb2 = fmaf(bv, bv, nb2);
    }
    #pragma unroll
    for (int off = 32; off > 0; off >>= 1) {
        dp += __shfl_down(dp, off);
        nb2 += __shfl_down(nb2, off);
    }
    if (lane == 0) {
        float nb = fmaxf(sqrtf(nb2), 1e-8f);
        float sim = dp / (nrm_a * nb);
        float lt = nll + ((pre != gold[t]) ? sim : 0.0f);
        loss_arr[t] = lt;
        d_out[t] = (float)pre;
    }
}

__global__ void reduce_loss_kernel(const float* __restrict__ loss_arr, float* __restrict__ out_loss) {
    __shared__ float sm[256];
    float s = 0.0f;
    for (int i = threadIdx.x; i < SS; i += 256) s += loss_arr[i];
    sm[threadIdx.x] = s;
    __syncthreads();
    for (int stp = 128; stp > 0; stp >>= 1) {
        if (threadIdx.x < stp) sm[threadIdx.x] += sm[threadIdx.x + stp];
        __syncthreads();
    }
    if (threadIdx.x == 0) out_loss[0] = sm[0];
}

extern "C" void kernel_launch(void* const* d_in, const int* in_sizes, int n_in,
                              void* d_out, int out_size, void* d_ws, size_t ws_size,
                              hipStream_t stream) {
    const float* x       = (const float*)d_in[0];
    const int*   gold    = (const int*)d_in[1];
    const float* Wih_f1  = (const float*)d_in[2];
    const float* Whh_f1  = (const float*)d_in[3];
    const float* bih_f1  = (const float*)d_in[4];
    const float* bhh_f1  = (const float*)d_in[5];
    const float* Wih_b1  = (const float*)d_in[6];
    const float* Whh_b1  = (const float*)d_in[7];
    const float* bih_b1  = (const float*)d_in[8];
    const float* bhh_b1  = (const float*)d_in[9];
    const float* Wih_f2  = (const float*)d_in[10];
    const float* Whh_f2  = (const float*)d_in[11];
    const float* bih_f2  = (const float*)d_in[12];
    const float* bhh_f2  = (const float*)d_in[13];
    const float* Wih_b2  = (const float*)d_in[14];
    const float* Whh_b2  = (const float*)d_in[15];
    const float* bih_b2  = (const float*)d_in[16];
    const float* bhh_b2  = (const float*)d_in[17];
    const float* W_out   = (const float*)d_in[18];
    const float* b_out   = (const float*)d_in[19];
    const float* last_rep= (const float*)d_in[20];

    float* ws = (float*)d_ws;
    float* Wkm      = ws;                         // 2*114*600*4 = 547200
    float* W2cat    = Wkm + 2 * NKC * G4 * 4;     // 2*600*152   = 182400
    float* sent_emb = W2cat + 2 * G4 * K2PAD;     // 1024*300    = 307200
    float* xw2      = sent_emb + SS * DD;         // 2*1024*600  = 1228800
    float* sent_out = xw2 + 2 * SS * G4;          // 1024*300    = 307200
    float* loss_arr = sent_out + SS * DD;         // 1024
    // total ~10.3 MB of workspace

    pack1_kernel<<<(2 * NKC * G4 + 255) / 256, 256, 0, stream>>>(Wih_f1, Whh_f1, Wih_b1, Whh_b1, Wkm);
    pack2_kernel<<<(2 * G4 * K2PAD + 255) / 256, 256, 0, stream>>>(Whh_f2, Whh_b2, W2cat);
    word_lstm_kernel<<<256, 640, 0, stream>>>(x, Wkm, bih_f1, bhh_f1, bih_b1, bhh_b1, sent_emb);
    xw2_kernel<<<2048, 256, 0, stream>>>(sent_emb, Wih_f2, bih_f2, bhh_f2, Wih_b2, bih_b2, bhh_b2, xw2);
    sent_lstm_kernel<<<2, 640, 0, stream>>>(W2cat, xw2, sent_out);
    loss_kernel<<<1024, 64, 0, stream>>>(sent_out, gold, W_out, b_out, last_rep, (float*)d_out, loss_arr);
    reduce_loss_kernel<<<1, 256, 0, stream>>>(loss_arr, (float*)d_out + SS);
}

// Round 10
// 7947.040 us; speedup vs baseline: 1.6889x; 1.3145x over previous
//
#include <hip/hip_runtime.h>
#include <math.h>

#define HH   150        // hidden per direction
#define G4   600        // 4*H
#define DD   300        // embedding dim
#define CLS  7
#define SS   1024       // sentences
#define WW   128        // words per sentence
#define KCAT 450        // D + H
#define KPAD 456        // padded k for stage-1 (114 float4 chunks)
#define NKC  114        // KPAD/4
#define K2PAD 152       // H padded to float4 multiple (38 chunks)

__device__ __forceinline__ float sigf(float x) {
    return 1.0f / (1.0f + exp2f(-1.44269504088896341f * x));
}
__device__ __forceinline__ float tanh_f(float x) {
    return 2.0f / (1.0f + exp2f(-2.88539008177792681f * x)) - 1.0f;
}

// ---------------- weight packing ----------------
// Wkm: k-major [2][NKC][600] float4: Wkm[dir][kc][r] = W[r][4kc..4kc+3]
// -> lanes (consecutive rows) load at 16/32B stride = coalesced streaming.
__global__ void pack1_kernel(const float* __restrict__ Wih_f, const float* __restrict__ Whh_f,
                             const float* __restrict__ Wih_b, const float* __restrict__ Whh_b,
                             float* __restrict__ Wkm) {
    int idx = blockIdx.x * 256 + threadIdx.x;   // one float4 per (dir,kc,r)
    const int total = 2 * NKC * G4;
    if (idx >= total) return;
    int r   = idx % G4;
    int kc  = (idx / G4) % NKC;
    int dir = idx / (G4 * NKC);
    const float* Wih = dir ? Wih_b : Wih_f;
    const float* Whh = dir ? Whh_b : Whh_f;
    float v[4];
    #pragma unroll
    for (int e = 0; e < 4; ++e) {
        int k = 4 * kc + e;
        float t = 0.0f;
        if (k < DD) t = Wih[r * DD + k];
        else if (k < KCAT) t = Whh[r * HH + (k - DD)];
        v[e] = t;
    }
    ((float4*)Wkm)[idx] = make_float4(v[0], v[1], v[2], v[3]);
}

// W2pk: float4 array [2][300][2(c)][2(r')][19(j)]. Lane-task (p,c) owns
// virtual rows vr=2p, 2p+1 for k-half c. Virtual row vr maps to physical
// row (vr&3)*150 + (vr>>2): unit u's 4 gates land on adjacent lanes 4u..4u+3.
__global__ void pack2_kernel(const float* __restrict__ Whh_f2, const float* __restrict__ Whh_b2,
                             float* __restrict__ W2pk) {
    int idx = blockIdx.x * 256 + threadIdx.x;   // one float4
    const int total = 2 * 300 * 2 * 2 * 19;     // 45600
    if (idx >= total) return;
    int j   = idx % 19;
    int t1  = idx / 19;
    int rp  = t1 & 1;
    int t2  = t1 >> 1;
    int c   = t2 & 1;
    int t3  = t2 >> 1;
    int p   = t3 % 300;
    int dir = t3 / 300;
    int vr  = 2 * p + rp;
    int row = (vr & 3) * HH + (vr >> 2);
    const float* Whh = dir ? Whh_b2 : Whh_f2;
    float v[4];
    #pragma unroll
    for (int e = 0; e < 4; ++e) {
        int k = 76 * c + 4 * j + e;
        v[e] = (k < HH) ? Whh[row * HH + k] : 0.0f;
    }
    ((float4*)W2pk)[idx] = make_float4(v[0], v[1], v[2], v[3]);
}

// ---------------- word-level BiLSTM (stage 1) ---------------- (unchanged, round-8)
__global__ __launch_bounds__(640, 1) void word_lstm_kernel(
    const float* __restrict__ x,        // [S][W][D]
    const float* __restrict__ Wkm,      // [2][NKC][600] float4 k-major
    const float* __restrict__ bih_f, const float* __restrict__ bhh_f,
    const float* __restrict__ bih_b, const float* __restrict__ bhh_b,
    float* __restrict__ sent_emb)       // [S][300]
{
    __shared__ __align__(16) float xh[8][KPAD];   // [x(300) | h(150) | pad0(6)]
    __shared__ __align__(16) float g[8][G4];
    __shared__ __align__(16) float cst[8][HH];
    __shared__ __align__(16) float hmax[8][HH];

    const int tid = threadIdx.x;
    const int dir = blockIdx.x & 1;
    const int sb  = blockIdx.x >> 1;
    const int s0  = sb * 8;

    const int grp   = (tid >= 320) ? 1 : 0;
    const int u     = tid - 320 * grp;       // 0..319
    const bool owner = (u < 300);
    const int sbase = 4 * grp;               // this thread's sentences [sbase, sbase+4)

    for (int i = tid; i < 8 * KPAD; i += 640) ((float*)xh)[i] = 0.0f;  // h0=0, pads=0
    for (int i = tid; i < 8 * HH; i += 640) {
        ((float*)cst)[i] = 0.0f;
        ((float*)hmax)[i] = -INFINITY;
    }

    const float4* wbase = ((const float4*)Wkm) + (size_t)dir * NKC * G4;
    float bias0 = 0.0f, bias1 = 0.0f;
    if (owner) {
        const int r0 = 2 * u, r1 = 2 * u + 1;
        if (dir) { bias0 = bih_b[r0] + bhh_b[r0]; bias1 = bih_b[r1] + bhh_b[r1]; }
        else     { bias0 = bih_f[r0] + bhh_f[r0]; bias1 = bih_f[r1] + bhh_f[r1]; }
    }

    // prologue: stage x for first time index
    {
        int t0 = (dir == 0) ? 0 : (WW - 1);
        __syncthreads();
        for (int i = tid; i < 8 * DD; i += 640) {
            int s = i / DD, d = i - s * DD;
            xh[s][d] = x[((size_t)(s0 + s) * WW + t0) * DD + d];
        }
    }
    __syncthreads();

    for (int st = 0; st < WW; ++st) {
        const int tt = (dir == 0) ? st : (WW - 1 - st);
        const int tn = (dir == 0) ? (tt + 1) : (tt - 1);
        const bool has_next = (st + 1 < WW);

        // prefetch next x into registers (2400 vals over 640 threads = 4 slots)
        float pf[4];
        if (has_next) {
            #pragma unroll
            for (int k = 0; k < 4; ++k) {
                int i = tid + k * 640;
                if (k < 3 || i < 8 * DD) {
                    int s = i / DD, d = i - s * DD;
                    pf[k] = x[((size_t)(s0 + s) * WW + tn) * DD + d];
                }
            }
        }

        // dot phase: g[s][r] = bias_r + [x|h] . W[r], 2 rows x 4 sentences
        if (owner) {
            float acc0[4], acc1[4];
            #pragma unroll
            for (int q = 0; q < 4; ++q) { acc0[q] = bias0; acc1[q] = bias1; }
            #pragma unroll 2
            for (int kc = 0; kc < NKC; ++kc) {
                float4 w0 = wbase[kc * G4 + 2 * u];
                float4 w1 = wbase[kc * G4 + 2 * u + 1];
                #pragma unroll
                for (int q = 0; q < 4; ++q) {
                    float4 xv = *((const float4*)&xh[sbase + q][kc * 4]);
                    acc0[q] = fmaf(w0.x, xv.x, acc0[q]);
                    acc0[q] = fmaf(w0.y, xv.y, acc0[q]);
                    acc0[q] = fmaf(w0.z, xv.z, acc0[q]);
                    acc0[q] = fmaf(w0.w, xv.w, acc0[q]);
                    acc1[q] = fmaf(w1.x, xv.x, acc1[q]);
                    acc1[q] = fmaf(w1.y, xv.y, acc1[q]);
                    acc1[q] = fmaf(w1.z, xv.z, acc1[q]);
                    acc1[q] = fmaf(w1.w, xv.w, acc1[q]);
                }
            }
            #pragma unroll
            for (int q = 0; q < 4; ++q) {
                *((float2*)&g[sbase + q][2 * u]) = make_float2(acc0[q], acc1[q]);
            }
        }
        __syncthreads();

        // gate phase: 1200 units over 640 threads
        for (int v = tid; v < 8 * HH; v += 640) {
            int s = v / HH, uu = v - s * HH;
            float gi = g[s][uu], gf = g[s][HH + uu], gg = g[s][2 * HH + uu], go = g[s][3 * HH + uu];
            float c = cst[s][uu];
            c = sigf(gf) * c + sigf(gi) * tanh_f(gg);
            float h = sigf(go) * tanh_f(c);
            cst[s][uu] = c;
            xh[s][DD + uu] = h;
            hmax[s][uu] = fmaxf(hmax[s][uu], h);
        }

        // write prefetched x for next step (disjoint from h region)
        if (has_next) {
            #pragma unroll
            for (int k = 0; k < 4; ++k) {
                int i = tid + k * 640;
                if (k < 3 || i < 8 * DD) {
                    int s = i / DD, d = i - s * DD;
                    xh[s][d] = pf[k];
                }
            }
        }
        __syncthreads();
    }

    for (int v = tid; v < 8 * HH; v += 640) {
        int s = v / HH, uu = v - s * HH;
        sent_emb[(size_t)(s0 + s) * DD + dir * HH + uu] = hmax[s][uu];
    }
}

// ---------------- stage-2 input projection ---------------- (unchanged)
__global__ void xw2_kernel(const float* __restrict__ sent_emb,
                           const float* __restrict__ Wih_f2, const float* __restrict__ bih_f2,
                           const float* __restrict__ bhh_f2,
                           const float* __restrict__ Wih_b2, const float* __restrict__ bih_b2,
                           const float* __restrict__ bhh_b2,
                           float* __restrict__ xw2) {
    __shared__ __align__(16) float xr[DD];
    const int t = blockIdx.x >> 1;
    const int dir = blockIdx.x & 1;
    const float* Wih2 = dir ? Wih_b2 : Wih_f2;
    const float* ba = dir ? bih_b2 : bih_f2;
    const float* bb = dir ? bhh_b2 : bhh_f2;
    for (int i = threadIdx.x; i < DD; i += 256) xr[i] = sent_emb[(size_t)t * DD + i];
    __syncthreads();
    for (int o = threadIdx.x; o < G4; o += 256) {
        float acc = ba[o] + bb[o];
        const float4* wr = (const float4*)(Wih2 + (size_t)o * DD);
        #pragma unroll 4
        for (int kc = 0; kc < DD / 4; ++kc) {
            float4 w4 = wr[kc];
            float4 xv = *((const float4*)&xr[kc * 4]);
            acc = fmaf(w4.x, xv.x, acc);
            acc = fmaf(w4.y, xv.y, acc);
            acc = fmaf(w4.z, xv.z, acc);
            acc = fmaf(w4.w, xv.w, acc);
        }
        xw2[((size_t)dir * SS + t) * G4 + o] = acc;
    }
}

// ---------------- sentence-level BiLSTM (stage 2) ----------------
// grid 2 (dir), block 640 (10 waves). v3: round-8 profile showed VGPR=84 ->
// weights were NOT register-resident (compiler sank the loads; 364 KB/step
// re-streamed from L2 ~6.5k cyc) and 38 b128 h-broadcasts x 10 waves cost
// ~4.5k cyc (1KB RF-writeback each). Fix:
//  (1) lane-task (p=tid>>1, c=tid&1): 2 virtual rows x 76-k-half = 152
//      weight floats, loaded once and PINNED via asm "+v" (cannot be
//      rematerialized as loads -> resident, minor spill at the 170-VGPR cap).
//  (2) each lane reads only its 76-float h-half (19 b128, 2-addr merged)
//      -> h-broadcast halves; partials combined with 2 shfl_xor.
//  (3) row permutation (pack2) puts unit u's gates on lanes 4u..4u+3 ->
//      gate exchange = 3 shfl_down, ONE barrier/step, h double-buffered.
__global__ __launch_bounds__(640, 1) void sent_lstm_kernel(
    const float* __restrict__ W2pk,     // [2][300][2][2][19] float4
    const float* __restrict__ xw2,      // [2][S][600]
    float* __restrict__ sent_out)       // [S][300]
{
    __shared__ __align__(16) float hl[2][K2PAD];
    const int dir  = blockIdx.x;
    const int tid  = threadIdx.x;
    const bool act = (tid < 600);
    const int p    = tid >> 1;          // pair index
    const int c    = tid & 1;           // k-half
    const int u    = tid >> 2;          // unit (for gate phase)
    const int gi   = tid & 3;           // gate of my virtual row vr = tid
    const int myrow = gi * HH + u;      // physical row for xw2 / g

    float4 w0[19], w1[19];              // vr=2p and vr=2p+1, k-half c
    if (act) {
        const float4* wb = ((const float4*)W2pk) + (((size_t)(dir * 300 + p) * 2 + c) * 2) * 19;
        #pragma unroll
        for (int j = 0; j < 19; ++j) { w0[j] = wb[j]; w1[j] = wb[19 + j]; }
    } else {
        #pragma unroll
        for (int j = 0; j < 19; ++j) { w0[j] = make_float4(0.f,0.f,0.f,0.f); w1[j] = w0[j]; }
    }
    // Pin: asm outputs cannot be re-materialized as loads -> stays in VGPRs.
    #pragma unroll
    for (int j = 0; j < 19; ++j) {
        asm volatile("" : "+v"(w0[j].x), "+v"(w0[j].y), "+v"(w0[j].z), "+v"(w0[j].w));
        asm volatile("" : "+v"(w1[j].x), "+v"(w1[j].y), "+v"(w1[j].z), "+v"(w1[j].w));
    }

    for (int i = tid; i < 2 * K2PAD; i += 640) ((float*)hl)[i] = 0.0f;
    float cstate = 0.0f;                // owned by gi==0 lanes

    float xwc = 0.0f;
    if (act) {
        const int t0 = dir ? (SS - 1) : 0;
        xwc = xw2[((size_t)dir * SS + t0) * G4 + myrow];
    }
    __syncthreads();

    int cur = 0;
    for (int st = 0; st < SS; ++st) {
        const int tt = dir ? (SS - 1 - st) : st;

        // prefetch next step's xw2 (off critical path)
        float xwn = 0.0f;
        if (st + 1 < SS && act) {
            const int tn = dir ? (SS - 2 - st) : (st + 1);
            xwn = xw2[((size_t)dir * SS + tn) * G4 + myrow];
        }

        // dot: partials for vr=2p (a0) and vr=2p+1 (a1) over my 76-k-half
        float a0 = 0.0f, a1 = 0.0f;
        if (act) {
            const float* hb = &hl[cur][76 * c];
            #pragma unroll
            for (int j = 0; j < 19; ++j) {
                float4 h4 = *((const float4*)(hb + 4 * j));
                a0 = fmaf(w0[j].x, h4.x, a0);
                a0 = fmaf(w0[j].y, h4.y, a0);
                a0 = fmaf(w0[j].z, h4.z, a0);
                a0 = fmaf(w0[j].w, h4.w, a0);
                a1 = fmaf(w1[j].x, h4.x, a1);
                a1 = fmaf(w1[j].y, h4.y, a1);
                a1 = fmaf(w1[j].z, h4.z, a1);
                a1 = fmaf(w1[j].w, h4.w, a1);
            }
        }
        // combine k-halves with partner lane (tid^1); keep my vr = 2p+c
        float g0 = a0 + __shfl_xor(a0, 1);
        float g1 = a1 + __shfl_xor(a1, 1);
        float gv = (c ? g1 : g0) + xwc;
        // gates of unit u live on lanes 4u..4u+3 (i,f,g,o)
        float gf = __shfl_down(gv, 1);
        float gg = __shfl_down(gv, 2);
        float go = __shfl_down(gv, 3);
        if (gi == 0 && act) {
            cstate = sigf(gf) * cstate + sigf(gv) * tanh_f(gg);
            float h = sigf(go) * tanh_f(cstate);
            hl[cur ^ 1][u] = h;
            sent_out[(size_t)tt * DD + dir * HH + u] = h;
        }
        __syncthreads();   // hl[cur] readers done; hl[cur^1] complete
        cur ^= 1;
        xwc = xwn;
    }
}

// ---------------- classification + loss ---------------- (unchanged)
__global__ void loss_kernel(const float* __restrict__ sent_out,
                            const int* __restrict__ gold,
                            const float* __restrict__ W_out, const float* __restrict__ b_out,
                            const float* __restrict__ last_rep,
                            float* __restrict__ d_out, float* __restrict__ loss_arr) {
    const int t = blockIdx.x;
    const int lane = threadIdx.x;
    const float* a = sent_out + (size_t)t * DD;

    float pl[CLS];
    #pragma unroll
    for (int j = 0; j < CLS; ++j) pl[j] = 0.0f;
    float na2 = 0.0f;
    for (int k = lane; k < DD; k += 64) {
        float av = a[k];
        na2 = fmaf(av, av, na2);
        #pragma unroll
        for (int j = 0; j < CLS; ++j) pl[j] = fmaf(av, W_out[j * DD + k], pl[j]);
    }
    #pragma unroll
    for (int off = 32; off > 0; off >>= 1) {
        na2 += __shfl_down(na2, off);
        #pragma unroll
        for (int j = 0; j < CLS; ++j) pl[j] += __shfl_down(pl[j], off);
    }

    int pre = 0;
    float nll = 0.0f, nrm_a = 1.0f;
    if (lane == 0) {
        float lg[CLS];
        float mx = -INFINITY;
        #pragma unroll
        for (int j = 0; j < CLS; ++j) {
            lg[j] = pl[j] + b_out[j];
            if (lg[j] > mx) mx = lg[j];
        }
        pre = 0;
        float bst = lg[0];
        #pragma unroll
        for (int j = 1; j < CLS; ++j) {       // first-max semantics (strict >)
            if (lg[j] > bst) { bst = lg[j]; pre = j; }
        }
        float se = 0.0f;
        #pragma unroll
        for (int j = 0; j < CLS; ++j) se += expf(lg[j] - mx);
        float lse = logf(se);
        nll = -(lg[gold[t]] - mx - lse);
        nrm_a = fmaxf(sqrtf(na2), 1e-8f);
    }
    pre = __shfl(pre, 0);

    const float* lr = last_rep + (size_t)pre * DD;
    float dp = 0.0f, nb2 = 0.0f;
    for (int k = lane; k < DD; k += 64) {
        float bv = lr[k];
        dp = fmaf(a[k], bv, dp);
        nb2 = fmaf(bv, bv, nb2);
    }
    #pragma unroll
    for (int off = 32; off > 0; off >>= 1) {
        dp += __shfl_down(dp, off);
        nb2 += __shfl_down(nb2, off);
    }
    if (lane == 0) {
        float nb = fmaxf(sqrtf(nb2), 1e-8f);
        float sim = dp / (nrm_a * nb);
        float lt = nll + ((pre != gold[t]) ? sim : 0.0f);
        loss_arr[t] = lt;
        d_out[t] = (float)pre;
    }
}

__global__ void reduce_loss_kernel(const float* __restrict__ loss_arr, float* __restrict__ out_loss) {
    __shared__ float sm[256];
    float s = 0.0f;
    for (int i = threadIdx.x; i < SS; i += 256) s += loss_arr[i];
    sm[threadIdx.x] = s;
    __syncthreads();
    for (int stp = 128; stp > 0; stp >>= 1) {
        if (threadIdx.x < stp) sm[threadIdx.x] += sm[threadIdx.x + stp];
        __syncthreads();
    }
    if (threadIdx.x == 0) out_loss[0] = sm[0];
}

extern "C" void kernel_launch(void* const* d_in, const int* in_sizes, int n_in,
                              void* d_out, int out_size, void* d_ws, size_t ws_size,
                              hipStream_t stream) {
    const float* x       = (const float*)d_in[0];
    const int*   gold    = (const int*)d_in[1];
    const float* Wih_f1  = (const float*)d_in[2];
    const float* Whh_f1  = (const float*)d_in[3];
    const float* bih_f1  = (const float*)d_in[4];
    const float* bhh_f1  = (const float*)d_in[5];
    const float* Wih_b1  = (const float*)d_in[6];
    const float* Whh_b1  = (const float*)d_in[7];
    const float* bih_b1  = (const float*)d_in[8];
    const float* bhh_b1  = (const float*)d_in[9];
    const float* Wih_f2  = (const float*)d_in[10];
    const float* Whh_f2  = (const float*)d_in[11];
    const float* bih_f2  = (const float*)d_in[12];
    const float* bhh_f2  = (const float*)d_in[13];
    const float* Wih_b2  = (const float*)d_in[14];
    const float* Whh_b2  = (const float*)d_in[15];
    const float* bih_b2  = (const float*)d_in[16];
    const float* bhh_b2  = (const float*)d_in[17];
    const float* W_out   = (const float*)d_in[18];
    const float* b_out   = (const float*)d_in[19];
    const float* last_rep= (const float*)d_in[20];

    float* ws = (float*)d_ws;
    float* Wkm      = ws;                         // 2*114*600*4 = 547200
    float* W2pk     = Wkm + 2 * NKC * G4 * 4;     // 45600 float4 = 182400
    float* sent_emb = W2pk + 2 * 300 * 2 * 2 * 19 * 4;  // 1024*300 = 307200
    float* xw2      = sent_emb + SS * DD;         // 2*1024*600  = 1228800
    float* sent_out = xw2 + 2 * SS * G4;          // 1024*300    = 307200
    float* loss_arr = sent_out + SS * DD;         // 1024
    // total ~10.3 MB of workspace

    pack1_kernel<<<(2 * NKC * G4 + 255) / 256, 256, 0, stream>>>(Wih_f1, Whh_f1, Wih_b1, Whh_b1, Wkm);
    pack2_kernel<<<(2 * 300 * 2 * 2 * 19 + 255) / 256, 256, 0, stream>>>(Whh_f2, Whh_b2, W2pk);
    word_lstm_kernel<<<256, 640, 0, stream>>>(x, Wkm, bih_f1, bhh_f1, bih_b1, bhh_b1, sent_emb);
    xw2_kernel<<<2048, 256, 0, stream>>>(sent_emb, Wih_f2, bih_f2, bhh_f2, Wih_b2, bih_b2, bhh_b2, xw2);
    sent_lstm_kernel<<<2, 640, 0, stream>>>(W2pk, xw2, sent_out);
    loss_kernel<<<1024, 64, 0, stream>>>(sent_out, gold, W_out, b_out, last_rep, (float*)d_out, loss_arr);
    reduce_loss_kernel<<<1, 256, 0, stream>>>(loss_arr, (float*)d_out + SS);
}